// Round 8
// baseline (228.014 us; speedup 1.0000x reference)
//
#include <hip/hip_runtime.h>
#include <hip/hip_bf16.h>

#define EPSF 1e-8f

__device__ __forceinline__ float wave_sum(float v) {
#pragma unroll
    for (int off = 32; off > 0; off >>= 1) v += __shfl_xor(v, off);
    return v;
}

__device__ __forceinline__ unsigned f2bf(float x) {           // RNE f32->bf16
    unsigned u = __builtin_bit_cast(unsigned, x);
    u += 0x7fffu + ((u >> 16) & 1u);
    return u >> 16;
}
__device__ __forceinline__ unsigned pk2(float a, float b) {   // bf16x2 pack
    return f2bf(a) | (f2bf(b) << 16);
}
__device__ __forceinline__ float bflo(unsigned u) {
    return __builtin_bit_cast(float, u << 16);
}
__device__ __forceinline__ float bfhi(unsigned u) {
    return __builtin_bit_cast(float, u & 0xffff0000u);
}
__device__ __forceinline__ float fast_tanh(float x) {         // |x| <= ~1
    float e = __expf(2.0f * x);
    return 1.0f - 2.0f / (e + 1.0f);
}

// ---------------- GEMM: [m;q](576x768) @ W^T(768x768) -> hm(+bias), hq ----------------
// Double-buffered LDS: one barrier per k-tile.
__global__ __launch_bounds__(256) void gemm_mq(
    const float* __restrict__ m, const float* __restrict__ q,
    const float* __restrict__ W, const float* __restrict__ b,
    float* __restrict__ hm, float* __restrict__ hq)
{
    __shared__ __align__(16) float As[2][32][32];   // [buf][k][m]
    __shared__ __align__(16) float Bs[2][32][64];   // [buf][k][n]
    const int t  = threadIdx.x;
    const int bm = blockIdx.x, bn = blockIdx.y;
    const int tc = t & 15, tr = t >> 4;

    const int arow = t & 31;
    const int ak   = (t >> 5) << 2;
    const int gr   = bm * 32 + arow;
    const float* abase = ((gr < 64) ? (m + gr * 768) : (q + (gr - 64) * 768)) + ak;

    const int jl  = t & 63;
    const int bk0 = ((t >> 6) & 3) << 2;
    const int bk1 = bk0 + 16;
    const float* bbase;
    {
        int j = bn * 64 + jl;
        int n = j / 192, d = j - n * 192;
        bbase = W + (size_t)n * 64 * 192 * 768 + (size_t)d * 768;
    }

    // preload + stage tile 0
    {
        float4 av  = *(const float4*)(abase);
        float4 bv0 = *(const float4*)(bbase + bk0);
        float4 bv1 = *(const float4*)(bbase + bk1);
        As[0][ak + 0][arow] = av.x;  As[0][ak + 1][arow] = av.y;
        As[0][ak + 2][arow] = av.z;  As[0][ak + 3][arow] = av.w;
        Bs[0][bk0 + 0][jl] = bv0.x;  Bs[0][bk0 + 1][jl] = bv0.y;
        Bs[0][bk0 + 2][jl] = bv0.z;  Bs[0][bk0 + 3][jl] = bv0.w;
        Bs[0][bk1 + 0][jl] = bv1.x;  Bs[0][bk1 + 1][jl] = bv1.y;
        Bs[0][bk1 + 2][jl] = bv1.z;  Bs[0][bk1 + 3][jl] = bv1.w;
    }
    __syncthreads();

    float acc[2][4] = {};
    for (int ks = 0; ks < 24; ++ks) {
        const int cur = ks & 1;
        float4 av, bv0, bv1;
        if (ks < 23) {
            av  = *(const float4*)(abase + (ks + 1) * 32);
            bv0 = *(const float4*)(bbase + (ks + 1) * 32 + bk0);
            bv1 = *(const float4*)(bbase + (ks + 1) * 32 + bk1);
        }
#pragma unroll
        for (int k = 0; k < 32; ++k) {
            float2 a2 = *(const float2*)&As[cur][k][2 * tr];
            float4 b4 = *(const float4*)&Bs[cur][k][4 * tc];
            acc[0][0] += a2.x * b4.x; acc[0][1] += a2.x * b4.y;
            acc[0][2] += a2.x * b4.z; acc[0][3] += a2.x * b4.w;
            acc[1][0] += a2.y * b4.x; acc[1][1] += a2.y * b4.y;
            acc[1][2] += a2.y * b4.z; acc[1][3] += a2.y * b4.w;
        }
        if (ks < 23) {
            const int nxt = cur ^ 1;
            As[nxt][ak + 0][arow] = av.x;  As[nxt][ak + 1][arow] = av.y;
            As[nxt][ak + 2][arow] = av.z;  As[nxt][ak + 3][arow] = av.w;
            Bs[nxt][bk0 + 0][jl] = bv0.x;  Bs[nxt][bk0 + 1][jl] = bv0.y;
            Bs[nxt][bk0 + 2][jl] = bv0.z;  Bs[nxt][bk0 + 3][jl] = bv0.w;
            Bs[nxt][bk1 + 0][jl] = bv1.x;  Bs[nxt][bk1 + 1][jl] = bv1.y;
            Bs[nxt][bk1 + 2][jl] = bv1.z;  Bs[nxt][bk1 + 3][jl] = bv1.w;
            __syncthreads();
        }
    }
#pragma unroll
    for (int i = 0; i < 2; ++i) {
        int r = bm * 32 + 2 * tr + i;
#pragma unroll
        for (int u = 0; u < 4; ++u) {
            int j = bn * 64 + 4 * tc + u;
            float v = acc[i][u];
            if (r < 64) {
                int n = j / 192, d = j - n * 192;
                int idx = (n * 64 + r) * 192 + d;
                hm[idx] = v + b[idx];
            } else {
                hq[(r - 64) * 768 + j] = v;
            }
        }
    }
}

// ---------------- fully fused routing: all 3 rounds, 2 queries x 4 capsules per block ----
// hm staged once as bf16-packed rows (96 u32 / row), uint4-slot swizzle k ^ (row&7).
// tq/v held 4-wide per lane (lanes 0..47: d = 4l..4l+3); pearson via D/tmean recursion.
// stats (s1,s2) and initial D fused into ONE pass over the hm row.
__global__ __launch_bounds__(512) void route_fused(
    const float* __restrict__ hm, const float* __restrict__ hq,
    float* __restrict__ out)
{
    __shared__ __align__(16) uint4 hs4[4 * 64 * 24];   // 96 KB
    __shared__ __align__(16) float wbuf[8][192];       //  6 KB (per-wave vector)
    __shared__ __align__(16) float wgt_x[8][64];       //  2 KB
    __shared__ __align__(16) float a_x[2][4][64];      //  2 KB

    const int t = threadIdx.x, w = t >> 6, l = t & 63;
    const int ql = w >> 2, n = w & 3;
    const int q  = blockIdx.x * 2 + ql;

    // ---- stage all of hm (192 KB f32 -> 96 KB bf16, swizzled) ----
    {
        const float4* src = (const float4*)hm;
#pragma unroll
        for (int i = 0; i < 12; ++i) {
            int f = t + 512 * i;               // packed-slot id 0..6143
            int r = f / 24, k = f - r * 24;    // row (n*64+c), slot
            float4 x0 = src[f * 2];
            float4 x1 = src[f * 2 + 1];
            uint4 pk;
            pk.x = pk2(x0.x, x0.y);
            pk.y = pk2(x0.z, x0.w);
            pk.z = pk2(x1.x, x1.y);
            pk.w = pk2(x1.z, x1.w);
            hs4[r * 24 + (k ^ (r & 7))] = pk;
        }
    }
    __syncthreads();

    const uint4* myrow = hs4 + (n * 64 + l) * 24;
    const int xo = l & 7;

    // dot(my hm row, wbuf[w])
    auto dotrow = [&]() -> float {
        float4 acc = {0.f, 0.f, 0.f, 0.f};
#pragma unroll 6
        for (int k = 0; k < 24; ++k) {
            uint4 h = myrow[k ^ xo];
            float4 wa = *(const float4*)&wbuf[w][k * 8];
            float4 wb = *(const float4*)&wbuf[w][k * 8 + 4];
            acc.x += bflo(h.x) * wa.x; acc.y += bfhi(h.x) * wa.y;
            acc.z += bflo(h.y) * wa.z; acc.w += bfhi(h.y) * wa.w;
            acc.x += bflo(h.z) * wb.x; acc.y += bfhi(h.z) * wb.y;
            acc.z += bflo(h.w) * wb.z; acc.w += bfhi(h.w) * wb.w;
        }
        return (acc.x + acc.y) + (acc.z + acc.w);
    };

    // ---- tq in 4-wide layout (lanes 0..47); raw tq into wbuf for the fused D pass ----
    const bool act = (l < 48);
    float t4x = 0.f, t4y = 0.f, t4z = 0.f, t4w = 0.f;
    if (act) {
        float4 tv = *(const float4*)(hq + q * 768 + n * 192 + 4 * l);
        t4x = tv.x; t4y = tv.y; t4z = tv.z; t4w = tv.w;
        *(float4*)&wbuf[w][4 * l] = tv;
    }
    float tmean = wave_sum((t4x + t4y) + (t4z + t4w)) * (1.0f / 192.0f);
    float t2s   = wave_sum((t4x*t4x + t4y*t4y) + (t4z*t4z + t4w*t4w));
    float sy    = t2s - 192.0f * tmean * tmean;

    // ---- fused single pass: s1 = sum hm, s2 = sum hm^2, D = dot(hm, tq) ----
    float s1 = 0.f, s2 = 0.f, D = 0.f;
#pragma unroll 6
    for (int k = 0; k < 24; ++k) {
        uint4 h = myrow[k ^ xo];
        float4 wa = *(const float4*)&wbuf[w][k * 8];
        float4 wb = *(const float4*)&wbuf[w][k * 8 + 4];
        float e0 = bflo(h.x), e1 = bfhi(h.x), e2 = bflo(h.y), e3 = bfhi(h.y);
        float e4 = bflo(h.z), e5 = bfhi(h.z), e6 = bflo(h.w), e7 = bfhi(h.w);
        s1 += ((e0 + e1) + (e2 + e3)) + ((e4 + e5) + (e6 + e7));
        s2 += ((e0*e0 + e1*e1) + (e2*e2 + e3*e3)) + ((e4*e4 + e5*e5) + (e6*e6 + e7*e7));
        D  += ((e0*wa.x + e1*wa.y) + (e2*wa.z + e3*wa.w))
            + ((e4*wb.x + e5*wb.y) + (e6*wb.z + e7*wb.w));
    }
    const float S = s1;
    const float hmmean = s1 * (1.0f / 192.0f);
    const float sx_c = s2 - 192.0f * hmmean * hmmean;

    float p = fast_tanh(-(D - tmean * S) * rsqrtf(sx_c * sy + EPSF));
    float a = 0.0f, dsm = 0.25f;                  // softmax(0) over 4

    // passA addressing: lane l<48 covers d = 4l..4l+3  (uint2 within one swizzled quad)
    const unsigned* rowbase = (const unsigned*)hs4 + n * 64 * 96;
    const int qk   = l >> 1;           // logical quad
    const int wsel = (l & 1) << 1;     // word-in-quad 0 or 2

    for (int r = 0; r < 3; ++r) {
        if (r > 0) {
            a_x[ql][n][l] = a;
            __syncthreads();
            float a0 = a_x[ql][0][l], a1 = a_x[ql][1][l];
            float a2 = a_x[ql][2][l], a3 = a_x[ql][3][l];
            __syncthreads();
            float mx = fmaxf(fmaxf(a0, a1), fmaxf(a2, a3));
            float e0 = __expf(a0 - mx), e1 = __expf(a1 - mx);
            float e2 = __expf(a2 - mx), e3 = __expf(a3 - mx);
            float my = (n == 0) ? e0 : (n == 1) ? e1 : (n == 2) ? e2 : e3;
            dsm = my / (e0 + e1 + e2 + e3);
        }
        wgt_x[w][l] = dsm + p;

        // passA: hv[d] = sum_c wgt[c]*hm[c][d], d = 4l..4l+3
        float hv0 = 0.f, hv1 = 0.f, hv2 = 0.f, hv3 = 0.f;
        if (act) {
#pragma unroll 8
            for (int c = 0; c < 64; ++c) {
                float wv = wgt_x[w][c];
                int base = c * 96 + ((qk ^ (c & 7)) << 2) + wsel;
                uint2 u = *(const uint2*)(rowbase + base);
                hv0 += wv * bflo(u.x); hv1 += wv * bfhi(u.x);
                hv2 += wv * bflo(u.y); hv3 += wv * bfhi(u.y);
            }
        }
        float sq = wave_sum((hv0*hv0 + hv1*hv1) + (hv2*hv2 + hv3*hv3));
        float scale = sq / ((1.0f + sq) * sqrtf(sq + EPSF));
        float v0 = hv0 * scale, v1 = hv1 * scale, v2 = hv2 * scale, v3 = hv3 * scale;

        if (r == 2) {
            if (act) {
                float4 ov = {v0, v1, v2, v3};
                *(float4*)(out + q * 768 + n * 192 + 4 * l) = ov;
            }
            break;
        }

        // agree = dot(hm row, v)
        if (act) {
            float4 vv = {v0, v1, v2, v3};
            *(float4*)&wbuf[w][4 * l] = vv;
        }
        float A = dotrow();
        a += p * A;

        // recursions: tq, D, tmean; fresh sy from registers
        t4x = (t4x + v0) * 0.5f; t4y = (t4y + v1) * 0.5f;
        t4z = (t4z + v2) * 0.5f; t4w = (t4w + v3) * 0.5f;
        float vmean = wave_sum((v0 + v1) + (v2 + v3)) * (1.0f / 192.0f);
        D = 0.5f * (D + A);
        tmean = 0.5f * (tmean + vmean);
        float t2s2 = wave_sum((t4x*t4x + t4y*t4y) + (t4z*t4z + t4w*t4w));
        sy = t2s2 - 192.0f * tmean * tmean;
        p = fast_tanh(-(D - tmean * S) * rsqrtf(sx_c * sy + EPSF));
    }
}

// ---------------- launch ----------------
extern "C" void kernel_launch(void* const* d_in, const int* in_sizes, int n_in,
                              void* d_out, int out_size, void* d_ws, size_t ws_size,
                              hipStream_t stream) {
    const float* m = (const float*)d_in[0];
    const float* q = (const float*)d_in[1];
    const float* W = (const float*)d_in[2];
    const float* b = (const float*)d_in[3];
    float* out = (float*)d_out;
    float* ws  = (float*)d_ws;

    const int Qn = in_sizes[1] / 768;      // 512

    float* hm = ws;                         // 4*64*192 = 49152 floats
    float* hq = ws + 49152;                 // Qn*768

    dim3 ggrid(18, 12);
    gemm_mq<<<ggrid, 256, 0, stream>>>(m, q, W, b, hm, hq);
    route_fused<<<Qn / 2, 512, 0, stream>>>(hm, hq, out);
}